// Round 9
// baseline (554.282 us; speedup 1.0000x reference)
//
#include <hip/hip_runtime.h>
#include <math.h>
#include <stdint.h>

#define NB 15
#define TROWS 512                 // rows per tile (2 per thread, processed serially)
#define TBYTES (TROWS * 40)       // 20480 B per tile
#define NCOPY 8                   // spread accumulator copies
#define ACCSTRIDE 64              // floats per copy

// d_ws: NCOPY copies of {[0..14]=counts,[15..29]=sum_u,[30..44]=sum_err}, then ticket int.
// LDS: single 20480 B tile buffer; floats [0..44] reused as s_acc and [46] as last-block
// flag in the epilogue (after a barrier). 20480 x 8 = 160 KiB exactly -> 8 blocks/CU.

__device__ __forceinline__ void gload_lds16(const void* g, float* ldsBase, uint32_t ldsByteOff)
{
    // async global->LDS, 16 B/lane; LDS dest = wave-uniform base + lane*16 (HW)
    __builtin_amdgcn_global_load_lds(
        (const __attribute__((address_space(1))) uint32_t*)g,
        (__attribute__((address_space(3))) uint32_t*)((char*)ldsBase + ldsByteOff),
        16, 0, 0);
}

__global__ __launch_bounds__(256, 8) void bin_kernel(   // min 8 waves/EU -> VGPR<=64
    const float* __restrict__ logits,
    const int* __restrict__ labels,
    float* __restrict__ acc,
    float* __restrict__ out,
    int N, int numTiles, int nBlocks)
{
    __shared__ float lds[TROWS * 10];      // 20480 B EXACT — nothing else in LDS

    const int t = threadIdx.x;
    const int wid  = t >> 6;
    const int lane = t & 63;

    int   pk[NB];                          // count | (err<<16); <=8 per bin per thread
    float su[NB];
#pragma unroll
    for (int b = 0; b < NB; ++b) { pk[b] = 0; su[b] = 0.0f; }

    const char* srcB = (const char*)logits;
    const long long totB = (long long)N * 40;

    // contiguous, balanced tile range per block (sequential 20KB streams per block)
    const int tileBeg = (int)((long long)blockIdx.x       * numTiles / nBlocks);
    const int tileEnd = (int)((long long)(blockIdx.x + 1) * numTiles / nBlocks);

    for (int tile = tileBeg; tile < tileEnd; ++tile) {
        const long long tb = (long long)tile * TBYTES;

        const int r0 = tile * TROWS + t;
        const int r1 = r0 + 256;
        const int lab0 = (r0 < N) ? labels[r0] : 0;   // issued before barrier (overlap)
        const int lab1 = (r1 < N) ? labels[r1] : 0;

        __syncthreads();                   // previous tile fully consumed
#pragma unroll
        for (int k = 0; k < 5; ++k) {      // 20 chunks of 1024 B, 5 per wave
            uint32_t loff = (uint32_t)(wid * 5 + k) << 10;
            long long gb = tb + loff + lane * 16;
            if (gb < totB)
                gload_lds16(srcB + gb, lds, __builtin_amdgcn_readfirstlane(loff));
        }
        __syncthreads();                   // DMA drained -> LDS tile ready

        // two rows per thread, processed SERIALLY (one lv[] live -> low VGPR)
#pragma unroll 1
        for (int h = 0; h < 2; ++h) {
            const int  rr  = tile * TROWS + t + (h << 8);
            const int  lab = h ? lab1 : lab0;
            const float* rp = lds + (t + (h << 8)) * 10;

            float lv[10];
            {
                const float2* p2 = (const float2*)rp;
#pragma unroll
                for (int j = 0; j < 5; ++j) { float2 w = p2[j]; lv[2*j] = w.x; lv[2*j+1] = w.y; }
            }
            float m = lv[0];
#pragma unroll
            for (int j = 1; j < 10; ++j) m = fmaxf(m, lv[j]);

            const float c = 1.44269504088896340736f;
            float mc = m * c;
            float Z = 0.0f, S = 0.0f;
#pragma unroll
            for (int j = 0; j < 10; ++j) {
                float e = exp2f(fmaf(lv[j], c, -mc));
                Z += e;
                S = fmaf(e, e, S);
            }
            float u = -log2f(S * __builtin_amdgcn_rcpf(Z * Z) + 1e-12f);

            bool valid = (rr < N) && (u >= 0.0f) && (u < 1.0f);
            int bin = -1;
            if (valid) { bin = (int)(u * 15.0f); if (bin > 14) bin = 14; }
            float uu = valid ? u : 0.0f;

            float lvl = rp[lab];                       // label logit, dynamic LDS read
            int inc = 1 + (((lvl != m) ? 1 : 0) << 16);
#pragma unroll
            for (int b = 0; b < NB; ++b) {
                bool ht = (bin == b);
                pk[b] += ht ? inc : 0;
                su[b] += ht ? uu : 0.0f;
            }
        }
    }

    // ---- epilogue: reuse LDS tile buffer as s_acc (all tile reads done) ----
    __syncthreads();
    if (t < 47) lds[t] = 0.0f;             // s_acc[0..44] + flag slot [46]
    __syncthreads();

#pragma unroll
    for (int b = 0; b < NB; ++b) {
        int   p = pk[b];
        float s = su[b];
#pragma unroll
        for (int off = 1; off < 64; off <<= 1) {
            p += __shfl_xor(p, off, 64);
            s += __shfl_xor(s, off, 64);
        }
        if (lane == 0) {
            atomicAdd(&lds[b],          (float)(p & 0xFFFF));
            atomicAdd(&lds[NB + b],     s);
            atomicAdd(&lds[2 * NB + b], (float)((unsigned)p >> 16));
        }
    }
    __syncthreads();
    if (t < 3 * NB) {
        float v = lds[t];
        if (v != 0.0f)
            atomicAdd(&acc[(blockIdx.x & (NCOPY - 1)) * ACCSTRIDE + t], v);
    }

    // ---- last-block finalize ----
    __threadfence();
    __syncthreads();                       // drains the global atomics (vmcnt) too
    if (t == 0) {
        int old = atomicAdd((int*)(acc + NCOPY * ACCSTRIDE), 1);
        ((int*)lds)[46] = (old == nBlocks - 1) ? 1 : 0;
    }
    __syncthreads();
    if (((int*)lds)[46] && t < 64) {
        int b = t;
        float gap = 0.0f;
        if (b < NB) {
            float cnt = 0.0f, sumu = 0.0f, serr = 0.0f;
#pragma unroll
            for (int cc = 0; cc < NCOPY; ++cc) {
                cnt  += atomicAdd(&acc[cc * ACCSTRIDE + b], 0.0f);        // coherent read
                sumu += atomicAdd(&acc[cc * ACCSTRIDE + NB + b], 0.0f);
                serr += atomicAdd(&acc[cc * ACCSTRIDE + 2 * NB + b], 0.0f);
            }
            if (cnt > 0.0f) {
                float u_b   = sumu / cnt;
                float err_b = serr / cnt;
                float inner = 2.0f * exp2f(-u_b) - 1.0f;
                if (inner < 0.0f) inner = 0.0f;
                float r_ref = 0.5f * (1.0f - sqrtf(inner));
                gap = fabsf(err_b - r_ref) * (cnt / (float)N);
            }
        }
#pragma unroll
        for (int off = 32; off >= 1; off >>= 1)
            gap += __shfl_xor(gap, off, 64);
        if (b == 0) out[0] = gap;
    }
}

extern "C" void kernel_launch(void* const* d_in, const int* in_sizes, int n_in,
                              void* d_out, int out_size, void* d_ws, size_t ws_size,
                              hipStream_t stream)
{
    const float* logits = (const float*)d_in[0];
    const int*   labels = (const int*)d_in[1];
    const int N = in_sizes[1];                  // labels count = number of rows

    float* acc = (float*)d_ws;                  // NCOPY*ACCSTRIDE floats + ticket
    hipMemsetAsync(acc, 0, (NCOPY * ACCSTRIDE + 1) * sizeof(float), stream);

    const int numTiles = (N + TROWS - 1) / TROWS;
    int blocks = numTiles < 2048 ? numTiles : 2048;   // 8 blocks/CU target
    bin_kernel<<<blocks, 256, 0, stream>>>(logits, labels, acc, (float*)d_out,
                                           N, numTiles, blocks);
}

// Round 10
// 506.834 us; speedup vs baseline: 1.0936x; 1.0936x over previous
//
#include <hip/hip_runtime.h>
#include <math.h>
#include <stdint.h>

#define NB 15
#define TROWS 512                 // rows per tile (2 per thread, processed serially)
#define TBYTES (TROWS * 40)       // 20480 B per tile
#define NCOPY 8                   // spread accumulator copies
#define ACCSTRIDE 64              // floats per copy

// d_ws: NCOPY copies of {[0..14]=counts,[15..29]=sum_u,[30..44]=sum_err}, then ticket int.
// LDS: single 20480 B tile buffer, reused as s_acc[0..44]+flag[46] in the epilogue.
// VGPR discipline: nibble-packed counts (4 regs) + su[15]; NO launch-bounds min-waves
// (R9 showed forcing 32 VGPR spills the accumulators -> 1.8x regression).

__device__ __forceinline__ void gload_lds16(const void* g, float* ldsBase, uint32_t ldsByteOff)
{
    // async global->LDS, 16 B/lane; LDS dest = wave-uniform base + lane*16 (HW)
    __builtin_amdgcn_global_load_lds(
        (const __attribute__((address_space(1))) uint32_t*)g,
        (__attribute__((address_space(3))) uint32_t*)((char*)ldsBase + ldsByteOff),
        16, 0, 0);
}

__global__ __launch_bounds__(256) void bin_kernel(
    const float* __restrict__ logits,
    const int* __restrict__ labels,
    float* __restrict__ acc,
    float* __restrict__ out,
    int N, int numTiles, int nBlocks)
{
    __shared__ float lds[TROWS * 10];      // 20480 B EXACT — nothing else in LDS

    const int t = threadIdx.x;
    const int wid  = t >> 6;
    const int lane = t & 63;

    // nibble-packed per-thread accumulators (max 2/tile x 4 tiles = 8 < 15 per bin)
    unsigned c01 = 0, c89 = 0, e01 = 0, e89 = 0;
    float su[NB];
#pragma unroll
    for (int b = 0; b < NB; ++b) su[b] = 0.0f;

    const char* srcB = (const char*)logits;
    const long long totB = (long long)N * 40;

    for (int tile = blockIdx.x; tile < numTiles; tile += gridDim.x) {
        const long long tb = (long long)tile * TBYTES;

        const int r0 = tile * TROWS + t;
        const int r1 = r0 + 256;
        const int lab0 = (r0 < N) ? labels[r0] : 0;   // issued before barrier (overlap)
        const int lab1 = (r1 < N) ? labels[r1] : 0;

        __syncthreads();                   // previous tile fully consumed
#pragma unroll
        for (int k = 0; k < 5; ++k) {      // 20 chunks of 1024 B, 5 per wave
            uint32_t loff = (uint32_t)(wid * 5 + k) << 10;
            long long gb = tb + loff + lane * 16;
            if (gb < totB)
                gload_lds16(srcB + gb, lds, __builtin_amdgcn_readfirstlane(loff));
        }
        __syncthreads();                   // DMA drained -> LDS tile ready

        // two rows per thread, processed SERIALLY (one lv[] live -> low VGPR)
#pragma unroll 1
        for (int h = 0; h < 2; ++h) {
            const int  rr  = tile * TROWS + t + (h << 8);
            const int  lab = h ? lab1 : lab0;
            const float* rp = lds + (t + (h << 8)) * 10;

            float lv[10];
            {
                const float2* p2 = (const float2*)rp;
#pragma unroll
                for (int j = 0; j < 5; ++j) { float2 w = p2[j]; lv[2*j] = w.x; lv[2*j+1] = w.y; }
            }
            float m = lv[0];
#pragma unroll
            for (int j = 1; j < 10; ++j) m = fmaxf(m, lv[j]);

            const float c = 1.44269504088896340736f;
            float mc = m * c;
            float Z = 0.0f, S = 0.0f;
#pragma unroll
            for (int j = 0; j < 10; ++j) {
                float e = exp2f(fmaf(lv[j], c, -mc));
                Z += e;
                S = fmaf(e, e, S);
            }
            float u = -log2f(S * __builtin_amdgcn_rcpf(Z * Z) + 1e-12f);

            bool valid = (rr < N) && (u >= 0.0f) && (u < 1.0f);
            int bin = -1;
            if (valid) { bin = (int)(u * 15.0f); if (bin > 14) bin = 14; }
            float uu = valid ? u : 0.0f;

            float lvl = rp[lab];                       // label logit, dynamic LDS read
            bool e10 = (lvl != m);                     // wrong iff label's isn't the max

            unsigned nib = valid ? (1u << ((bin & 7) << 2)) : 0u;
            bool lo = ((unsigned)bin < 8u);            // bin=-1 -> false, nib=0 anyway
            c01 += lo ? nib : 0u;
            c89 += lo ? 0u : nib;
            unsigned en = e10 ? nib : 0u;
            e01 += lo ? en : 0u;
            e89 += lo ? 0u : en;
#pragma unroll
            for (int b = 0; b < NB; ++b)
                su[b] += (bin == b) ? uu : 0.0f;
        }
    }

    // ---- epilogue: reuse LDS tile buffer as s_acc (all tile reads done) ----
    __syncthreads();
    if (t < 47) lds[t] = 0.0f;             // s_acc[0..44] + flag slot [46]
    __syncthreads();

#pragma unroll
    for (int b = 0; b < NB; ++b) {
        unsigned c4 = (b < 8) ? (c01 >> (b * 4)) : (c89 >> ((b - 8) * 4));
        unsigned e4 = (b < 8) ? (e01 >> (b * 4)) : (e89 >> ((b - 8) * 4));
        int   p = (int)((c4 & 15u) | ((e4 & 15u) << 16));
        float s = su[b];
#pragma unroll
        for (int off = 1; off < 64; off <<= 1) {
            p += __shfl_xor(p, off, 64);
            s += __shfl_xor(s, off, 64);
        }
        if (lane == 0) {
            atomicAdd(&lds[b],          (float)(p & 0xFFFF));
            atomicAdd(&lds[NB + b],     s);
            atomicAdd(&lds[2 * NB + b], (float)((unsigned)p >> 16));
        }
    }
    __syncthreads();
    if (t < 3 * NB) {
        float v = lds[t];
        if (v != 0.0f)
            atomicAdd(&acc[(blockIdx.x & (NCOPY - 1)) * ACCSTRIDE + t], v);
    }

    // ---- last-block finalize ----
    __threadfence();
    __syncthreads();
    if (t == 0) {
        int old = atomicAdd((int*)(acc + NCOPY * ACCSTRIDE), 1);
        ((int*)lds)[46] = (old == nBlocks - 1) ? 1 : 0;
    }
    __syncthreads();
    if (((int*)lds)[46] && t < 64) {
        int b = t;
        float gap = 0.0f;
        if (b < NB) {
            float cnt = 0.0f, sumu = 0.0f, serr = 0.0f;
#pragma unroll
            for (int cc = 0; cc < NCOPY; ++cc) {
                cnt  += atomicAdd(&acc[cc * ACCSTRIDE + b], 0.0f);        // coherent read
                sumu += atomicAdd(&acc[cc * ACCSTRIDE + NB + b], 0.0f);
                serr += atomicAdd(&acc[cc * ACCSTRIDE + 2 * NB + b], 0.0f);
            }
            if (cnt > 0.0f) {
                float u_b   = sumu / cnt;
                float err_b = serr / cnt;
                float inner = 2.0f * exp2f(-u_b) - 1.0f;
                if (inner < 0.0f) inner = 0.0f;
                float r_ref = 0.5f * (1.0f - sqrtf(inner));
                gap = fabsf(err_b - r_ref) * (cnt / (float)N);
            }
        }
#pragma unroll
        for (int off = 32; off >= 1; off >>= 1)
            gap += __shfl_xor(gap, off, 64);
        if (b == 0) out[0] = gap;
    }
}

extern "C" void kernel_launch(void* const* d_in, const int* in_sizes, int n_in,
                              void* d_out, int out_size, void* d_ws, size_t ws_size,
                              hipStream_t stream)
{
    const float* logits = (const float*)d_in[0];
    const int*   labels = (const int*)d_in[1];
    const int N = in_sizes[1];                  // labels count = number of rows

    float* acc = (float*)d_ws;                  // NCOPY*ACCSTRIDE floats + ticket
    hipMemsetAsync(acc, 0, (NCOPY * ACCSTRIDE + 1) * sizeof(float), stream);

    const int numTiles = (N + TROWS - 1) / TROWS;
    int blocks = numTiles < 2048 ? numTiles : 2048;   // <=4 tiles/thread -> nibble-safe
    bin_kernel<<<blocks, 256, 0, stream>>>(logits, labels, acc, (float*)d_out,
                                           N, numTiles, blocks);
}